// Round 1
// baseline (665.837 us; speedup 1.0000x reference)
//
#include <hip/hip_runtime.h>
#include <hip/hip_bf16.h>

#define DQ 13
#define DKV 32
#define T_CTX 24
#define A_DIM 32
#define H_HEADS 4
#define O_DIM 32
#define NB 16               // batch elements per block
#define ROWS (NB * T_CTX)   // 384 kv rows per block
#define LN_EPS 1e-5f

typedef __attribute__((ext_vector_type(8))) short short8;
typedef __attribute__((ext_vector_type(4))) float float4v;

__device__ __forceinline__ short f2bf_s(float f) {
    __hip_bfloat16 h = __float2bfloat16(f);
    union { __hip_bfloat16 h; short s; } u; u.h = h;
    return u.s;
}
__device__ __forceinline__ float bf2f(unsigned short v) {
    unsigned int x = ((unsigned int)v) << 16;
    return __uint_as_float(x);
}
__device__ __forceinline__ float gelu_exact(float x) {
    return 0.5f * x * (1.0f + erff(x * 0.70710678118654752440f));
}

__global__ __launch_bounds__(256, 2)
void cross_dmha_fused(const float* __restrict__ query,
                      const float* __restrict__ kv,
                      const float* __restrict__ Wq,
                      const float* __restrict__ Wk,
                      const float* __restrict__ Wv,
                      const float* __restrict__ Wo,
                      const float* __restrict__ ln_w,
                      const float* __restrict__ ln_b,
                      const float* __restrict__ Wd1,
                      const float* __restrict__ Wd2,
                      float* __restrict__ out)
{
    __shared__ float s_q[NB * 32];                 // 2 KB   q projections
    __shared__ float s_qe[NB * 128];               // 8 KB   q_eff[e][h][D]
    __shared__ float s_sc[NB * H_HEADS * T_CTX];   // 6 KB   scores -> attn
    __shared__ unsigned short s_v[ROWS * 33];      // 25.3 KB v (bf16, padded)
    __shared__ float s_ctx[NB * 32];               // 2 KB
    __shared__ float s_y[NB * 32];                 // 2 KB   LN output
    __shared__ float s_h1[NB * 32];                // 2 KB   MLP hidden
    __shared__ float s_wk[32 * 32];                // 4 KB
    __shared__ float s_wo[32 * 32];                // 4 KB
    __shared__ float s_wd1[32 * 32];               // 4 KB
    __shared__ float s_wd2[32 * 32];               // 4 KB
    // total ~64.2 KB -> 2 blocks/CU on 160 KB LDS

    const int tid = threadIdx.x;
    const int l = tid & 63;
    const int w = tid >> 6;
    const int b0 = blockIdx.x * NB;
    const int quad = l >> 4;
    const int lm = l & 15;

    // ---- stage weights to LDS ----
    for (int j = tid; j < 1024; j += 256) {
        s_wk[j]  = Wk[j];
        s_wo[j]  = Wo[j];
        s_wd1[j] = Wd1[j];
        s_wd2[j] = Wd2[j];
    }

    // ---- Wv as MFMA B-fragments (per-lane registers) ----
    // B[k][n]: lane holds n = l&15, k = (l>>4)*8 + j
    short8 bfrag0, bfrag1;
    #pragma unroll
    for (int j = 0; j < 8; ++j) {
        int k = quad * 8 + j;
        bfrag0[j] = f2bf_s(Wv[k * 32 + lm]);
        bfrag1[j] = f2bf_s(Wv[k * 32 + 16 + lm]);
    }
    __syncthreads();

    // ---- q projection: thread -> (e = tid>>4, cols m and m+16) ----
    {
        int e = tid >> 4, m = tid & 15;
        const float* qrow = query + (size_t)(b0 + e) * DQ;
        float acc0 = 0.f, acc1 = 0.f;
        #pragma unroll
        for (int d = 0; d < DQ; ++d) {
            float qq = qrow[d];
            acc0 += qq * Wq[d * 32 + m];
            acc1 += qq * Wq[d * 32 + m + 16];
        }
        s_q[e * 32 + m] = acc0;
        s_q[e * 32 + m + 16] = acc1;
    }
    __syncthreads();

    // ---- q_eff[e][h][D] = (1/sqrt(8)) * sum_d q[e][h*8+d] * Wk[D][h*8+d] ----
    {
        int e = tid >> 4, m = tid & 15;
        int h = m >> 2, D0 = (m & 3) * 8;
        const float scale = 0.35355339059327373f; // 1/sqrt(8)
        #pragma unroll
        for (int Di = 0; Di < 8; ++Di) {
            int D = D0 + Di;
            float acc = 0.f;
            #pragma unroll
            for (int d = 0; d < 8; ++d)
                acc += s_q[e * 32 + h * 8 + d] * s_wk[D * 32 + h * 8 + d];
            s_qe[e * 128 + h * 32 + D] = acc * scale;
        }
    }
    __syncthreads();

    // ---- main loop: stream kv rows once; MFMA v-proj + VALU scores ----
    // A-frag (16x16x32): lane holds row m = l&15, k = quad*8 + j
    for (int it = 0; it < 6; ++it) {
        int tile = w * 6 + it;          // 24 M-tiles of 16 rows
        int r0 = tile * 16;
        int row = r0 + lm;              // local kv row (b-major, t-minor)
        const float* src = kv + ((size_t)b0 * T_CTX + row) * DKV + quad * 8;
        float4v f0 = *reinterpret_cast<const float4v*>(src);
        float4v f1 = *reinterpret_cast<const float4v*>(src + 4);
        float av[8] = {f0[0], f0[1], f0[2], f0[3], f1[0], f1[1], f1[2], f1[3]};
        short8 afrag;
        #pragma unroll
        for (int j = 0; j < 8; ++j) afrag[j] = f2bf_s(av[j]);

        float4v c0 = {0.f, 0.f, 0.f, 0.f};
        float4v c1 = {0.f, 0.f, 0.f, 0.f};
        c0 = __builtin_amdgcn_mfma_f32_16x16x32_bf16(afrag, bfrag0, c0, 0, 0, 0);
        c1 = __builtin_amdgcn_mfma_f32_16x16x32_bf16(afrag, bfrag1, c1, 0, 0, 0);

        // C layout: col = lane&15, row = quad*4 + reg
        #pragma unroll
        for (int i = 0; i < 4; ++i) {
            int rw = r0 + quad * 4 + i;
            s_v[rw * 33 + lm]      = (unsigned short)f2bf_s(c0[i]);
            s_v[rw * 33 + 16 + lm] = (unsigned short)f2bf_s(c1[i]);
        }

        // scores: per-lane partial over its 8 D's, reduce across quads
        int e = row / T_CTX;
        int t = row - e * T_CTX;
        const float* qe_base = &s_qe[e * 128 + quad * 8];
        #pragma unroll
        for (int h = 0; h < H_HEADS; ++h) {
            const float* qe = qe_base + h * 32;
            float p = 0.f;
            #pragma unroll
            for (int j = 0; j < 8; ++j) p += av[j] * qe[j];
            p += __shfl_xor(p, 16);
            p += __shfl_xor(p, 32);
            if (quad == 0) s_sc[e * 96 + h * 24 + t] = p;
        }
    }
    __syncthreads();

    // ---- softmax over t for each (e, h) ----
    if (tid < NB * H_HEADS) {
        int e = tid >> 2, h = tid & 3;
        float* sc = &s_sc[e * 96 + h * 24];
        float mx = sc[0];
        #pragma unroll
        for (int t = 1; t < T_CTX; ++t) mx = fmaxf(mx, sc[t]);
        float ex[T_CTX];
        float sum = 0.f;
        #pragma unroll
        for (int t = 0; t < T_CTX; ++t) { ex[t] = __expf(sc[t] - mx); sum += ex[t]; }
        float inv = 1.f / sum;
        #pragma unroll
        for (int t = 0; t < T_CTX; ++t) sc[t] = ex[t] * inv;
    }
    __syncthreads();

    // ---- ctx[e][a] = sum_t attn[e][a>>3][t] * v[e*24+t][a] ----
    {
        int e = tid >> 4, a0 = tid & 15;
        #pragma unroll
        for (int aa = 0; aa < 2; ++aa) {
            int a = a0 + aa * 16;
            int h = a >> 3;
            const float* at = &s_sc[e * 96 + h * 24];
            float acc = 0.f;
            #pragma unroll
            for (int t = 0; t < T_CTX; ++t)
                acc += at[t] * bf2f(s_v[(e * 24 + t) * 33 + a]);
            s_ctx[e * 32 + a] = acc;
        }
    }
    __syncthreads();

    // ---- out = ctx @ Wo, then LayerNorm (shuffle reduction within e-group) ----
    {
        int e = tid >> 4, o0 = tid & 15;
        float out0 = 0.f, out1 = 0.f;
        #pragma unroll
        for (int c = 0; c < 32; ++c) {
            float cv = s_ctx[e * 32 + c];
            out0 += cv * s_wo[c * 32 + o0];
            out1 += cv * s_wo[c * 32 + o0 + 16];
        }
        float tot = out0 + out1;
        tot += __shfl_xor(tot, 1);
        tot += __shfl_xor(tot, 2);
        tot += __shfl_xor(tot, 4);
        tot += __shfl_xor(tot, 8);
        float mu = tot * (1.f / 32.f);
        float d0 = out0 - mu, d1 = out1 - mu;
        float sq = d0 * d0 + d1 * d1;
        sq += __shfl_xor(sq, 1);
        sq += __shfl_xor(sq, 2);
        sq += __shfl_xor(sq, 4);
        sq += __shfl_xor(sq, 8);
        float rstd = rsqrtf(sq * (1.f / 32.f) + LN_EPS);
        float y0 = d0 * rstd * ln_w[o0] + ln_b[o0];
        float y1 = d1 * rstd * ln_w[o0 + 16] + ln_b[o0 + 16];
        s_y[e * 32 + o0] = y0;
        s_y[e * 32 + o0 + 16] = y1;
    }
    __syncthreads();

    // ---- MLP layer 1: h1 = gelu(y @ Wd1) ----
    {
        int e = tid >> 4, o0 = tid & 15;
        float a0 = 0.f, a1 = 0.f;
        #pragma unroll
        for (int c = 0; c < 32; ++c) {
            float yv = s_y[e * 32 + c];
            a0 += yv * s_wd1[c * 32 + o0];
            a1 += yv * s_wd1[c * 32 + o0 + 16];
        }
        s_h1[e * 32 + o0] = gelu_exact(a0);
        s_h1[e * 32 + o0 + 16] = gelu_exact(a1);
    }
    __syncthreads();

    // ---- MLP layer 2 + residual + store ----
    {
        int e = tid >> 4, o0 = tid & 15;
        float a0 = 0.f, a1 = 0.f;
        #pragma unroll
        for (int c = 0; c < 32; ++c) {
            float hv = s_h1[e * 32 + c];
            a0 += hv * s_wd2[c * 32 + o0];
            a1 += hv * s_wd2[c * 32 + o0 + 16];
        }
        float r0v = s_y[e * 32 + o0] + gelu_exact(a0);
        float r1v = s_y[e * 32 + o0 + 16] + gelu_exact(a1);
        size_t ob = (size_t)(b0 + e) * 32;
        out[ob + o0] = r0v;
        out[ob + o0 + 16] = r1v;
    }
}

extern "C" void kernel_launch(void* const* d_in, const int* in_sizes, int n_in,
                              void* d_out, int out_size, void* d_ws, size_t ws_size,
                              hipStream_t stream) {
    const float* query = (const float*)d_in[0];
    const float* kv    = (const float*)d_in[1];
    const float* Wq    = (const float*)d_in[2];
    const float* Wk    = (const float*)d_in[3];
    const float* Wv    = (const float*)d_in[4];
    const float* Wo    = (const float*)d_in[5];
    const float* ln_w  = (const float*)d_in[6];
    const float* ln_b  = (const float*)d_in[7];
    const float* Wd1   = (const float*)d_in[8];
    const float* Wd2   = (const float*)d_in[9];
    float* out = (float*)d_out;

    int B = in_sizes[0] / DQ;           // 131072
    int grid = B / NB;                  // 8192
    cross_dmha_fused<<<grid, 256, 0, stream>>>(
        query, kv, Wq, Wk, Wv, Wo, ln_w, ln_b, Wd1, Wd2, out);
}

// Round 2
// 599.933 us; speedup vs baseline: 1.1099x; 1.1099x over previous
//
#include <hip/hip_runtime.h>
#include <hip/hip_bf16.h>

#define LN_EPS 1e-5f

typedef __attribute__((ext_vector_type(8))) short short8;
typedef __attribute__((ext_vector_type(4))) float float4v;
typedef __attribute__((ext_vector_type(2))) unsigned int uint2v;

__device__ __forceinline__ short f2bf(float f) {
    union { __hip_bfloat16 h; short s; } u; u.h = __float2bfloat16(f); return u.s;
}
__device__ __forceinline__ float bfbits2f(unsigned short v) {
    return __uint_as_float(((unsigned int)v) << 16);
}
__device__ __forceinline__ void split8(const float* x, short8& hi, short8& lo) {
    #pragma unroll
    for (int j = 0; j < 8; ++j) {
        short h = f2bf(x[j]);
        hi[j] = h;
        lo[j] = f2bf(x[j] - bfbits2f((unsigned short)h));
    }
}
__device__ __forceinline__ uint2v pack4(float4v v) {
    unsigned a = ((unsigned)(unsigned short)f2bf(v[0])) | (((unsigned)(unsigned short)f2bf(v[1])) << 16);
    unsigned b = ((unsigned)(unsigned short)f2bf(v[2])) | (((unsigned)(unsigned short)f2bf(v[3])) << 16);
    uint2v r; r[0] = a; r[1] = b; return r;
}
// dot of 4 bf16 attn weights with 4 bf16 v values (both packed 2x dword)
__device__ __forceinline__ float dot4(uint2v a, uint2v v) {
    float s;
    s  = __uint_as_float(a[0] << 16)          * __uint_as_float(v[0] << 16);
    s += __uint_as_float(a[0] & 0xffff0000u)  * __uint_as_float(v[0] & 0xffff0000u);
    s += __uint_as_float(a[1] << 16)          * __uint_as_float(v[1] << 16);
    s += __uint_as_float(a[1] & 0xffff0000u)  * __uint_as_float(v[1] & 0xffff0000u);
    return s;
}
__device__ __forceinline__ float gelu_exact(float x) {
    return 0.5f * x * (1.0f + erff(x * 0.70710678118654752440f));
}

// Wave-local design: each wave owns 4 batch elements end-to-end.
// All GEMMs on MFMA (weights as per-lane B-fragments in registers).
// V kept in registers (bf16 packed) across softmax; LDS only for small
// cross-lane handoffs (q_eff, scores, attn, ctx, y) -- all padded + vectorized.
__global__ __launch_bounds__(256, 3)
void cross_dmha_fused(const float* __restrict__ query,
                      const float* __restrict__ kv,
                      const float* __restrict__ Wq,
                      const float* __restrict__ Wk,
                      const float* __restrict__ Wv,
                      const float* __restrict__ Wo,
                      const float* __restrict__ lnw,
                      const float* __restrict__ lnb,
                      const float* __restrict__ Wd1,
                      const float* __restrict__ Wd2,
                      float* __restrict__ out)
{
    // per-wave slices (4 waves/block)
    __shared__ __align__(16) float s_q  [4][4 * 36];   // [w][e][col], stride 36
    __shared__ __align__(16) short s_qe [4][4 * 136];  // [w][e][h*32+D] bf16, stride 136
    __shared__ __align__(16) float s_sc [4][4 * 144];  // [w][e][h*36+t] fp32
    __shared__ __align__(16) short s_at [4][4 * 160];  // [w][e][h*40+t] bf16 (t padded to 32)
    __shared__ __align__(16) float s_ctx[4][4 * 36];
    __shared__ __align__(16) float s_y  [4][4 * 36];

    const int tid = threadIdx.x;
    const int l = tid & 63;
    const int w = tid >> 6;
    const int lm = l & 15;
    const int quad = l >> 4;
    const int E0 = blockIdx.x * 16 + w * 4;   // first batch element of this wave

    float* sq  = s_q[w];  short* sqe = s_qe[w];
    float* ssc = s_sc[w]; short* sat = s_at[w];
    float* sctx = s_ctx[w]; float* sy = s_y[w];

    const float4v z = {0.f, 0.f, 0.f, 0.f};

    // ---- weight B-fragments in registers: B[k=quad*8+j][n=lm (+16)] ----
    short8 wv0, wv1, woh0, wol0, woh1, wol1, wd1a, wd1b, wd2a, wd2b;
    #pragma unroll
    for (int j = 0; j < 8; ++j) {
        int k8 = quad * 8 + j;
        wv0[j] = f2bf(Wv[k8 * 32 + lm]);
        wv1[j] = f2bf(Wv[k8 * 32 + 16 + lm]);
        float wo0 = Wo[k8 * 32 + lm], wo1 = Wo[k8 * 32 + 16 + lm];
        short h0 = f2bf(wo0); woh0[j] = h0; wol0[j] = f2bf(wo0 - bfbits2f((unsigned short)h0));
        short h1 = f2bf(wo1); woh1[j] = h1; wol1[j] = f2bf(wo1 - bfbits2f((unsigned short)h1));
        wd1a[j] = f2bf(Wd1[k8 * 32 + lm]);
        wd1b[j] = f2bf(Wd1[k8 * 32 + 16 + lm]);
        wd2a[j] = f2bf(Wd2[k8 * 32 + lm]);
        wd2b[j] = f2bf(Wd2[k8 * 32 + 16 + lm]);
    }

    // ---- q projection: lane group (e=quad) computes q[e][lm], q[e][lm+16] ----
    {
        int e = quad;
        const float* qr = query + (size_t)(E0 + e) * 13;
        float a0 = 0.f, a1 = 0.f;
        #pragma unroll
        for (int d = 0; d < 13; ++d) {
            float qq = qr[d];
            a0 += qq * Wq[d * 32 + lm];
            a1 += qq * Wq[d * 32 + 16 + lm];
        }
        sq[e * 36 + lm] = a0;
        sq[e * 36 + 16 + lm] = a1;
    }
    __syncthreads();

    // ---- q_eff[e][h][D] = (1/sqrt8) * sum_d q[e][h*8+d]*Wk[D][h*8+d], bf16 ----
    {
        int e = quad, h = lm >> 2, D0 = (lm & 3) * 8;
        float4v q0 = *(const float4v*)&sq[e * 36 + h * 8];
        float4v q1 = *(const float4v*)&sq[e * 36 + h * 8 + 4];
        short8 p;
        #pragma unroll
        for (int Di = 0; Di < 8; ++Di) {
            const float* wr = Wk + (D0 + Di) * 32 + h * 8;
            float4v k0 = *(const float4v*)wr;
            float4v k1 = *(const float4v*)(wr + 4);
            float acc = q0[0]*k0[0] + q0[1]*k0[1] + q0[2]*k0[2] + q0[3]*k0[3]
                      + q1[0]*k1[0] + q1[1]*k1[1] + q1[2]*k1[2] + q1[3]*k1[3];
            p[Di] = f2bf(acc * 0.35355339059327373f);
        }
        *(short8*)&sqe[e * 136 + lm * 8] = p;   // [e][h*32+D0]
    }
    __syncthreads();

    // ---- main loop: per element, MFMA V-proj (A hi/lo) + MFMA scores ----
    uint2v vpk[4][4];   // [e][{h0c0,h0c1,h1c0,h1c1}] bf16-packed V C-frags
    #pragma unroll
    for (int e = 0; e < 4; ++e) {
        short8 qf = {0,0,0,0,0,0,0,0};
        if (lm < 4) qf = *(const short8*)&sqe[e * 136 + lm * 32 + quad * 8];

        const float* kvb = kv + (size_t)(E0 + e) * 24 * 32 + quad * 8;
        float x0[8];
        {
            const float* src = kvb + lm * 32;     // t = lm (0..15)
            float4v f0 = *(const float4v*)src, f1 = *(const float4v*)(src + 4);
            x0[0]=f0[0]; x0[1]=f0[1]; x0[2]=f0[2]; x0[3]=f0[3];
            x0[4]=f1[0]; x0[5]=f1[1]; x0[6]=f1[2]; x0[7]=f1[3];
        }
        float x1[8] = {0,0,0,0,0,0,0,0};
        if (lm < 8) {                              // t = 16+lm (16..23)
            const float* src = kvb + (16 + lm) * 32;
            float4v f0 = *(const float4v*)src, f1 = *(const float4v*)(src + 4);
            x1[0]=f0[0]; x1[1]=f0[1]; x1[2]=f0[2]; x1[3]=f0[3];
            x1[4]=f1[0]; x1[5]=f1[1]; x1[6]=f1[2]; x1[7]=f1[3];
        }
        short8 ah0, al0, ah1, al1;
        split8(x0, ah0, al0);
        split8(x1, ah1, al1);

        float4v v00 = __builtin_amdgcn_mfma_f32_16x16x32_bf16(al0, wv0, z, 0, 0, 0);
        v00 = __builtin_amdgcn_mfma_f32_16x16x32_bf16(ah0, wv0, v00, 0, 0, 0);
        float4v v01 = __builtin_amdgcn_mfma_f32_16x16x32_bf16(al0, wv1, z, 0, 0, 0);
        v01 = __builtin_amdgcn_mfma_f32_16x16x32_bf16(ah0, wv1, v01, 0, 0, 0);
        float4v v10 = __builtin_amdgcn_mfma_f32_16x16x32_bf16(al1, wv0, z, 0, 0, 0);
        v10 = __builtin_amdgcn_mfma_f32_16x16x32_bf16(ah1, wv0, v10, 0, 0, 0);
        float4v v11 = __builtin_amdgcn_mfma_f32_16x16x32_bf16(al1, wv1, z, 0, 0, 0);
        v11 = __builtin_amdgcn_mfma_f32_16x16x32_bf16(ah1, wv1, v11, 0, 0, 0);

        float4v sc0 = __builtin_amdgcn_mfma_f32_16x16x32_bf16(ah0, qf, z, 0, 0, 0);
        float4v sc1 = __builtin_amdgcn_mfma_f32_16x16x32_bf16(ah1, qf, z, 0, 0, 0);

        vpk[e][0] = pack4(v00);  // v[t=quad*4+i][a=lm]
        vpk[e][1] = pack4(v01);  // a=lm+16
        vpk[e][2] = pack4(v10);  // t=16+quad*4+i
        vpk[e][3] = pack4(v11);

        if (lm < 4) {            // scores: C col=h(=lm), row=t(quad*4+i)
            *(float4v*)&ssc[e * 144 + lm * 36 + quad * 4] = sc0;
            if (quad < 2)
                *(float4v*)&ssc[e * 144 + lm * 36 + 16 + quad * 4] = sc1;
        }
    }
    __syncthreads();

    // ---- batched softmax: 16 lanes, one (e,h) each ----
    if (l < 16) {
        int e = l >> 2, h = l & 3;
        const float* sc = &ssc[e * 144 + h * 36];
        float4v r[6];
        #pragma unroll
        for (int b = 0; b < 6; ++b) r[b] = *(const float4v*)&sc[b * 4];
        float mx = -1e30f;
        #pragma unroll
        for (int b = 0; b < 6; ++b)
            #pragma unroll
            for (int i = 0; i < 4; ++i) mx = fmaxf(mx, r[b][i]);
        float ex[24]; float sum = 0.f;
        #pragma unroll
        for (int b = 0; b < 6; ++b)
            #pragma unroll
            for (int i = 0; i < 4; ++i) { float v = __expf(r[b][i] - mx); ex[b*4+i] = v; sum += v; }
        float inv = 1.f / sum;
        short8 p[4];
        #pragma unroll
        for (int t = 0; t < 24; ++t) p[t >> 3][t & 7] = f2bf(ex[t] * inv);
        #pragma unroll
        for (int t = 24; t < 32; ++t) p[t >> 3][t & 7] = 0;
        short* dst = &sat[e * 160 + h * 40];
        *(short8*)&dst[0]  = p[0];
        *(short8*)&dst[8]  = p[1];
        *(short8*)&dst[16] = p[2];
        *(short8*)&dst[24] = p[3];
    }
    __syncthreads();

    // ---- ctx: v in regs x attn from LDS; cross-quad reduce ----
    #pragma unroll
    for (int e = 0; e < 4; ++e) {
        int hA = lm >> 3, hB = 2 + (lm >> 3);
        uint2v a00 = *(const uint2v*)&sat[e * 160 + hA * 40 + quad * 4];
        uint2v a01 = *(const uint2v*)&sat[e * 160 + hB * 40 + quad * 4];
        uint2v a10 = *(const uint2v*)&sat[e * 160 + hA * 40 + 16 + quad * 4];
        uint2v a11 = *(const uint2v*)&sat[e * 160 + hB * 40 + 16 + quad * 4];
        float pc0 = dot4(a00, vpk[e][0]) + dot4(a10, vpk[e][2]);
        float pc1 = dot4(a01, vpk[e][1]) + dot4(a11, vpk[e][3]);
        pc0 += __shfl_xor(pc0, 16); pc0 += __shfl_xor(pc0, 32);
        pc1 += __shfl_xor(pc1, 16); pc1 += __shfl_xor(pc1, 32);
        if (l < 16) {
            sctx[e * 36 + lm] = pc0;
            sctx[e * 36 + 16 + lm] = pc1;
        }
    }
    __syncthreads();

    // ---- out = ctx @ Wo via MFMA (A rows 0-3 = elements; hi/lo 3-product) ----
    short8 cah = {0,0,0,0,0,0,0,0}, cal = {0,0,0,0,0,0,0,0};
    if (lm < 4) {
        float cx[8];
        float4v c0 = *(const float4v*)&sctx[lm * 36 + quad * 8];
        float4v c1 = *(const float4v*)&sctx[lm * 36 + quad * 8 + 4];
        cx[0]=c0[0]; cx[1]=c0[1]; cx[2]=c0[2]; cx[3]=c0[3];
        cx[4]=c1[0]; cx[5]=c1[1]; cx[6]=c1[2]; cx[7]=c1[3];
        split8(cx, cah, cal);
    }
    float4v o0 = __builtin_amdgcn_mfma_f32_16x16x32_bf16(cal, woh0, z, 0, 0, 0);
    o0 = __builtin_amdgcn_mfma_f32_16x16x32_bf16(cah, wol0, o0, 0, 0, 0);
    o0 = __builtin_amdgcn_mfma_f32_16x16x32_bf16(cah, woh0, o0, 0, 0, 0);
    float4v o1 = __builtin_amdgcn_mfma_f32_16x16x32_bf16(cal, woh1, z, 0, 0, 0);
    o1 = __builtin_amdgcn_mfma_f32_16x16x32_bf16(cah, wol1, o1, 0, 0, 0);
    o1 = __builtin_amdgcn_mfma_f32_16x16x32_bf16(cah, woh1, o1, 0, 0, 0);

    // ---- LayerNorm: reduce over 16 lanes (cols) per C-row ----
    float lw0 = lnw[lm], lw1 = lnw[16 + lm], lb0 = lnb[lm], lb1 = lnb[16 + lm];
    float y0r[4], y1r[4];
    #pragma unroll
    for (int i = 0; i < 4; ++i) {
        float tot = o0[i] + o1[i];
        tot += __shfl_xor(tot, 1); tot += __shfl_xor(tot, 2);
        tot += __shfl_xor(tot, 4); tot += __shfl_xor(tot, 8);
        float mu = tot * (1.f / 32.f);
        float d0 = o0[i] - mu, d1 = o1[i] - mu;
        float sqs = d0 * d0 + d1 * d1;
        sqs += __shfl_xor(sqs, 1); sqs += __shfl_xor(sqs, 2);
        sqs += __shfl_xor(sqs, 4); sqs += __shfl_xor(sqs, 8);
        float rstd = rsqrtf(sqs * (1.f / 32.f) + LN_EPS);
        y0r[i] = d0 * rstd * lw0 + lb0;
        y1r[i] = d1 * rstd * lw1 + lb1;
    }
    if (l < 16) {   // quad 0 holds the valid rows (elements 0-3)
        #pragma unroll
        for (int i = 0; i < 4; ++i) { sy[i * 36 + lm] = y0r[i]; sy[i * 36 + 16 + lm] = y1r[i]; }
    }
    __syncthreads();

    // ---- MLP1: gelu(y @ Wd1)  (A hi/lo, B bf16) ----
    short8 yah = {0,0,0,0,0,0,0,0}, yal = {0,0,0,0,0,0,0,0};
    if (lm < 4) {
        float yx[8];
        float4v a = *(const float4v*)&sy[lm * 36 + quad * 8];
        float4v b = *(const float4v*)&sy[lm * 36 + quad * 8 + 4];
        yx[0]=a[0]; yx[1]=a[1]; yx[2]=a[2]; yx[3]=a[3];
        yx[4]=b[0]; yx[5]=b[1]; yx[6]=b[2]; yx[7]=b[3];
        split8(yx, yah, yal);
    }
    float4v g0 = __builtin_amdgcn_mfma_f32_16x16x32_bf16(yal, wd1a, z, 0, 0, 0);
    g0 = __builtin_amdgcn_mfma_f32_16x16x32_bf16(yah, wd1a, g0, 0, 0, 0);
    float4v g1 = __builtin_amdgcn_mfma_f32_16x16x32_bf16(yal, wd1b, z, 0, 0, 0);
    g1 = __builtin_amdgcn_mfma_f32_16x16x32_bf16(yah, wd1b, g1, 0, 0, 0);
    float h0r[4], h1r[4];
    #pragma unroll
    for (int i = 0; i < 4; ++i) { h0r[i] = gelu_exact(g0[i]); h1r[i] = gelu_exact(g1[i]); }
    __syncthreads();            // y fragment reads done; safe to overwrite s_y
    if (l < 16) {
        #pragma unroll
        for (int i = 0; i < 4; ++i) { sy[i * 36 + lm] = h0r[i]; sy[i * 36 + 16 + lm] = h1r[i]; }
    }
    __syncthreads();

    // ---- MLP2 + residual + store ----
    short8 hah = {0,0,0,0,0,0,0,0}, hal = {0,0,0,0,0,0,0,0};
    if (lm < 4) {
        float hx[8];
        float4v a = *(const float4v*)&sy[lm * 36 + quad * 8];
        float4v b = *(const float4v*)&sy[lm * 36 + quad * 8 + 4];
        hx[0]=a[0]; hx[1]=a[1]; hx[2]=a[2]; hx[3]=a[3];
        hx[4]=b[0]; hx[5]=b[1]; hx[6]=b[2]; hx[7]=b[3];
        split8(hx, hah, hal);
    }
    float4v m0 = __builtin_amdgcn_mfma_f32_16x16x32_bf16(hal, wd2a, z, 0, 0, 0);
    m0 = __builtin_amdgcn_mfma_f32_16x16x32_bf16(hah, wd2a, m0, 0, 0, 0);
    float4v m1 = __builtin_amdgcn_mfma_f32_16x16x32_bf16(hal, wd2b, z, 0, 0, 0);
    m1 = __builtin_amdgcn_mfma_f32_16x16x32_bf16(hah, wd2b, m1, 0, 0, 0);

    if (l < 16) {
        #pragma unroll
        for (int i = 0; i < 4; ++i) {
            float f0 = y0r[i] + gelu_exact(m0[i]);
            float f1 = y1r[i] + gelu_exact(m1[i]);
            size_t ob = (size_t)(E0 + i) * 32;
            out[ob + lm] = f0;
            out[ob + 16 + lm] = f1;
        }
    }
}

extern "C" void kernel_launch(void* const* d_in, const int* in_sizes, int n_in,
                              void* d_out, int out_size, void* d_ws, size_t ws_size,
                              hipStream_t stream) {
    const float* query = (const float*)d_in[0];
    const float* kv    = (const float*)d_in[1];
    const float* Wq    = (const float*)d_in[2];
    const float* Wk    = (const float*)d_in[3];
    const float* Wv    = (const float*)d_in[4];
    const float* Wo    = (const float*)d_in[5];
    const float* ln_w  = (const float*)d_in[6];
    const float* ln_b  = (const float*)d_in[7];
    const float* Wd1   = (const float*)d_in[8];
    const float* Wd2   = (const float*)d_in[9];
    float* out = (float*)d_out;

    int B = in_sizes[0] / 13;        // 131072
    int grid = B / 16;               // 8192 blocks, 4 waves x 4 elements
    cross_dmha_fused<<<grid, 256, 0, stream>>>(
        query, kv, Wq, Wk, Wv, Wo, ln_w, ln_b, Wd1, Wd2, out);
}

// Round 3
// 563.847 us; speedup vs baseline: 1.1809x; 1.0640x over previous
//
#include <hip/hip_runtime.h>
#include <hip/hip_bf16.h>

#define LN_EPS 1e-5f

typedef __attribute__((ext_vector_type(8))) short short8;
typedef __attribute__((ext_vector_type(4))) float float4v;
typedef __attribute__((ext_vector_type(2))) unsigned int uint2v;

// wave-internal LDS sync: one wave = one instruction stream, so after all
// outstanding LDS ops retire every lane sees every lane's writes.
#define WAVE_SYNC() asm volatile("s_waitcnt lgkmcnt(0)" ::: "memory")

__device__ __forceinline__ short f2bf(float f) {
    union { __hip_bfloat16 h; short s; } u; u.h = __float2bfloat16(f); return u.s;
}
__device__ __forceinline__ float bfbits2f(unsigned short v) {
    return __uint_as_float(((unsigned int)v) << 16);
}
__device__ __forceinline__ unsigned packpair(float a, float b) {
    union { __hip_bfloat162 h2; unsigned u; } t;
    t.h2 = __float22bfloat162_rn(make_float2(a, b));
    return t.u;
}
__device__ __forceinline__ short8 cvt8(float4v a, float4v b) {
    union { unsigned u; short s[2]; } t;
    short8 r;
    t.u = packpair(a[0], a[1]); r[0] = t.s[0]; r[1] = t.s[1];
    t.u = packpair(a[2], a[3]); r[2] = t.s[0]; r[3] = t.s[1];
    t.u = packpair(b[0], b[1]); r[4] = t.s[0]; r[5] = t.s[1];
    t.u = packpair(b[2], b[3]); r[6] = t.s[0]; r[7] = t.s[1];
    return r;
}
__device__ __forceinline__ void split8(const float* x, short8& hi, short8& lo) {
    #pragma unroll
    for (int j = 0; j < 8; ++j) {
        short h = f2bf(x[j]);
        hi[j] = h;
        lo[j] = f2bf(x[j] - bfbits2f((unsigned short)h));
    }
}
__device__ __forceinline__ uint2v pack4(float4v v) {
    uint2v r; r[0] = packpair(v[0], v[1]); r[1] = packpair(v[2], v[3]); return r;
}
__device__ __forceinline__ float dot4(uint2v a, uint2v v) {
    float s;
    s  = __uint_as_float(a[0] << 16)         * __uint_as_float(v[0] << 16);
    s += __uint_as_float(a[0] & 0xffff0000u) * __uint_as_float(v[0] & 0xffff0000u);
    s += __uint_as_float(a[1] << 16)         * __uint_as_float(v[1] << 16);
    s += __uint_as_float(a[1] & 0xffff0000u) * __uint_as_float(v[1] & 0xffff0000u);
    return s;
}
__device__ __forceinline__ float gelu_exact(float x) {
    return 0.5f * x * (1.0f + erff(x * 0.70710678118654752440f));
}

// Each wave owns 4 batch elements through attention (V kept in registers);
// wave 0 then runs the epilogue (Wo+LN+MLP) for all 16 block elements with
// full 16-row MFMAs. Only ONE block-wide barrier (ctx handoff); all other
// handoffs are wave-internal (s_waitcnt lgkmcnt(0)).
__global__ __launch_bounds__(256, 4)
void cross_dmha_fused(const float* __restrict__ query,
                      const float* __restrict__ kv,
                      const float* __restrict__ Wq,
                      const float* __restrict__ Wk,
                      const float* __restrict__ Wv,
                      const float* __restrict__ Wo,
                      const float* __restrict__ lnw,
                      const float* __restrict__ lnb,
                      const float* __restrict__ Wd1,
                      const float* __restrict__ Wd2,
                      float* __restrict__ out)
{
    __shared__ __align__(16) float s_q  [4][4 * 36];   // per-wave
    __shared__ __align__(16) short s_qe [4][4 * 136];  // per-wave
    __shared__ __align__(16) float s_sc [4][4 * 144];  // per-wave
    __shared__ __align__(16) short s_at [4][4 * 160];  // per-wave
    __shared__ __align__(16) float s_ctxb[16 * 36];    // block-level (then reused for h)
    __shared__ __align__(16) float s_yb  [16 * 36];    // epilogue y

    const int tid = threadIdx.x;
    const int l = tid & 63;
    const int w = tid >> 6;
    const int lm = l & 15;
    const int quad = l >> 4;
    const int B0 = blockIdx.x * 16;
    const int E0 = B0 + w * 4;

    float* sq = s_q[w];  short* sqe = s_qe[w];
    float* ssc = s_sc[w]; short* sat = s_at[w];
    const float4v z = {0.f, 0.f, 0.f, 0.f};

    // ---- Wv B-fragments: B[k=quad*8+j][n=lm (+16)] ----
    short8 wv0, wv1;
    #pragma unroll
    for (int j = 0; j < 8; ++j) {
        int k8 = quad * 8 + j;
        wv0[j] = f2bf(Wv[k8 * 32 + lm]);
        wv1[j] = f2bf(Wv[k8 * 32 + 16 + lm]);
    }

    // ---- q projection: e = quad ----
    {
        const float* qr = query + (size_t)(E0 + quad) * 13;
        float a0 = 0.f, a1 = 0.f;
        #pragma unroll
        for (int d = 0; d < 13; ++d) {
            float qq = qr[d];
            a0 += qq * Wq[d * 32 + lm];
            a1 += qq * Wq[d * 32 + 16 + lm];
        }
        sq[quad * 36 + lm] = a0;
        sq[quad * 36 + 16 + lm] = a1;
    }
    WAVE_SYNC();

    // ---- q_eff[e][h][D] = (1/sqrt8) * sum_d q[e][h*8+d]*Wk[D][h*8+d] ----
    {
        int h = lm >> 2, D0 = (lm & 3) * 8;
        float4v q0 = *(const float4v*)&sq[quad * 36 + h * 8];
        float4v q1 = *(const float4v*)&sq[quad * 36 + h * 8 + 4];
        short8 p;
        #pragma unroll
        for (int Di = 0; Di < 8; ++Di) {
            const float* wr = Wk + (D0 + Di) * 32 + h * 8;
            float4v k0 = *(const float4v*)wr;
            float4v k1 = *(const float4v*)(wr + 4);
            float acc = q0[0]*k0[0] + q0[1]*k0[1] + q0[2]*k0[2] + q0[3]*k0[3]
                      + q1[0]*k1[0] + q1[1]*k1[1] + q1[2]*k1[2] + q1[3]*k1[3];
            p[Di] = f2bf(acc * 0.35355339059327373f);
        }
        *(short8*)&sqe[quad * 136 + lm * 8] = p;
    }
    WAVE_SYNC();

    // ---- main loop: V-proj + scores via MFMA, V stays in registers ----
    uint2v vpk[4][4];
    #pragma unroll
    for (int e = 0; e < 4; ++e) {
        short8 qf = {0,0,0,0,0,0,0,0};
        if (lm < 4) qf = *(const short8*)&sqe[e * 136 + lm * 32 + quad * 8];

        const float* kvb = kv + ((size_t)(E0 + e) * 24) * 32 + quad * 8;
        float4v f0a = *(const float4v*)(kvb + lm * 32);
        float4v f0b = *(const float4v*)(kvb + lm * 32 + 4);
        float4v f1a = z, f1b = z;
        if (lm < 8) {
            f1a = *(const float4v*)(kvb + (16 + lm) * 32);
            f1b = *(const float4v*)(kvb + (16 + lm) * 32 + 4);
        }
        short8 ah0 = cvt8(f0a, f0b);
        short8 ah1 = cvt8(f1a, f1b);

        float4v v00 = __builtin_amdgcn_mfma_f32_16x16x32_bf16(ah0, wv0, z, 0, 0, 0);
        float4v v01 = __builtin_amdgcn_mfma_f32_16x16x32_bf16(ah0, wv1, z, 0, 0, 0);
        float4v v10 = __builtin_amdgcn_mfma_f32_16x16x32_bf16(ah1, wv0, z, 0, 0, 0);
        float4v v11 = __builtin_amdgcn_mfma_f32_16x16x32_bf16(ah1, wv1, z, 0, 0, 0);
        float4v sc0 = __builtin_amdgcn_mfma_f32_16x16x32_bf16(ah0, qf, z, 0, 0, 0);
        float4v sc1 = __builtin_amdgcn_mfma_f32_16x16x32_bf16(ah1, qf, z, 0, 0, 0);

        vpk[e][0] = pack4(v00);   // v[t=quad*4+i][a=lm]
        vpk[e][1] = pack4(v01);   // a=lm+16
        vpk[e][2] = pack4(v10);   // t=16+quad*4+i
        vpk[e][3] = pack4(v11);

        if (lm < 4) {             // scores: col=h(=lm), row=t
            *(float4v*)&ssc[e * 144 + lm * 36 + quad * 4] = sc0;
            if (quad < 2)
                *(float4v*)&ssc[e * 144 + lm * 36 + 16 + quad * 4] = sc1;
        }
    }
    WAVE_SYNC();

    // ---- softmax: 16 lanes, one (e,h) each ----
    if (l < 16) {
        int e = l >> 2, h = l & 3;
        const float* sc = &ssc[e * 144 + h * 36];
        float4v r[6];
        #pragma unroll
        for (int b = 0; b < 6; ++b) r[b] = *(const float4v*)&sc[b * 4];
        float mx = -1e30f;
        #pragma unroll
        for (int b = 0; b < 6; ++b)
            #pragma unroll
            for (int i = 0; i < 4; ++i) mx = fmaxf(mx, r[b][i]);
        float ex[24]; float sum = 0.f;
        #pragma unroll
        for (int b = 0; b < 6; ++b)
            #pragma unroll
            for (int i = 0; i < 4; ++i) { float v = __expf(r[b][i] - mx); ex[b*4+i] = v; sum += v; }
        float inv = 1.f / sum;
        short8 p[4];
        #pragma unroll
        for (int t = 0; t < 24; ++t) p[t >> 3][t & 7] = f2bf(ex[t] * inv);
        #pragma unroll
        for (int t = 24; t < 32; ++t) p[t >> 3][t & 7] = 0;
        short* dst = &sat[e * 160 + h * 40];
        *(short8*)&dst[0]  = p[0];
        *(short8*)&dst[8]  = p[1];
        *(short8*)&dst[16] = p[2];
        *(short8*)&dst[24] = p[3];
    }
    WAVE_SYNC();

    // ---- ctx: registers x attn; write to BLOCK-level LDS ----
    #pragma unroll
    for (int e = 0; e < 4; ++e) {
        int hA = lm >> 3, hB = 2 + hA;
        uint2v a00 = *(const uint2v*)&sat[e * 160 + hA * 40 + quad * 4];
        uint2v a01 = *(const uint2v*)&sat[e * 160 + hB * 40 + quad * 4];
        uint2v a10 = *(const uint2v*)&sat[e * 160 + hA * 40 + 16 + quad * 4];
        uint2v a11 = *(const uint2v*)&sat[e * 160 + hB * 40 + 16 + quad * 4];
        float pc0 = dot4(a00, vpk[e][0]) + dot4(a10, vpk[e][2]);
        float pc1 = dot4(a01, vpk[e][1]) + dot4(a11, vpk[e][3]);
        pc0 += __shfl_xor(pc0, 16); pc0 += __shfl_xor(pc0, 32);
        pc1 += __shfl_xor(pc1, 16); pc1 += __shfl_xor(pc1, 32);
        if (l < 16) {
            s_ctxb[(w * 4 + e) * 36 + lm] = pc0;
            s_ctxb[(w * 4 + e) * 36 + 16 + lm] = pc1;
        }
    }
    __syncthreads();           // the ONLY block-wide barrier
    if (w != 0) return;        // waves 1-3 done; wave 0 runs the epilogue

    // ======== epilogue: wave 0, all 16 elements, full 16-row MFMAs ========
    short8 woh0, wol0, woh1, wol1, wd1a, wd1b, wd2a, wd2b;
    #pragma unroll
    for (int j = 0; j < 8; ++j) {
        int k8 = quad * 8 + j;
        float wo0 = Wo[k8 * 32 + lm], wo1 = Wo[k8 * 32 + 16 + lm];
        short h0 = f2bf(wo0); woh0[j] = h0; wol0[j] = f2bf(wo0 - bfbits2f((unsigned short)h0));
        short h1 = f2bf(wo1); woh1[j] = h1; wol1[j] = f2bf(wo1 - bfbits2f((unsigned short)h1));
        wd1a[j] = f2bf(Wd1[k8 * 32 + lm]);
        wd1b[j] = f2bf(Wd1[k8 * 32 + 16 + lm]);
        wd2a[j] = f2bf(Wd2[k8 * 32 + lm]);
        wd2b[j] = f2bf(Wd2[k8 * 32 + 16 + lm]);
    }

    // ctx A-frag: row m=lm (16 elements), k = quad*8+j; hi/lo 3-product
    float cx[8];
    {
        float4v c0 = *(const float4v*)&s_ctxb[lm * 36 + quad * 8];
        float4v c1 = *(const float4v*)&s_ctxb[lm * 36 + quad * 8 + 4];
        cx[0]=c0[0]; cx[1]=c0[1]; cx[2]=c0[2]; cx[3]=c0[3];
        cx[4]=c1[0]; cx[5]=c1[1]; cx[6]=c1[2]; cx[7]=c1[3];
    }
    short8 cah, cal; split8(cx, cah, cal);
    float4v o0 = __builtin_amdgcn_mfma_f32_16x16x32_bf16(cal, woh0, z, 0, 0, 0);
    o0 = __builtin_amdgcn_mfma_f32_16x16x32_bf16(cah, wol0, o0, 0, 0, 0);
    o0 = __builtin_amdgcn_mfma_f32_16x16x32_bf16(cah, woh0, o0, 0, 0, 0);
    float4v o1 = __builtin_amdgcn_mfma_f32_16x16x32_bf16(cal, woh1, z, 0, 0, 0);
    o1 = __builtin_amdgcn_mfma_f32_16x16x32_bf16(cah, wol1, o1, 0, 0, 0);
    o1 = __builtin_amdgcn_mfma_f32_16x16x32_bf16(cah, woh1, o1, 0, 0, 0);

    // LayerNorm: row = element (quad*4+i), col = lm / lm+16
    float lw0 = lnw[lm], lw1 = lnw[16 + lm], lb0 = lnb[lm], lb1 = lnb[16 + lm];
    float y0r[4], y1r[4];
    #pragma unroll
    for (int i = 0; i < 4; ++i) {
        float tot = o0[i] + o1[i];
        tot += __shfl_xor(tot, 1); tot += __shfl_xor(tot, 2);
        tot += __shfl_xor(tot, 4); tot += __shfl_xor(tot, 8);
        float mu = tot * (1.f / 32.f);
        float d0 = o0[i] - mu, d1 = o1[i] - mu;
        float sqs = d0 * d0 + d1 * d1;
        sqs += __shfl_xor(sqs, 1); sqs += __shfl_xor(sqs, 2);
        sqs += __shfl_xor(sqs, 4); sqs += __shfl_xor(sqs, 8);
        float rstd = rsqrtf(sqs * (1.f / 32.f) + LN_EPS);
        y0r[i] = d0 * rstd * lw0 + lb0;
        y1r[i] = d1 * rstd * lw1 + lb1;
    }
    #pragma unroll
    for (int i = 0; i < 4; ++i) {
        s_yb[(quad * 4 + i) * 36 + lm] = y0r[i];
        s_yb[(quad * 4 + i) * 36 + 16 + lm] = y1r[i];
    }
    WAVE_SYNC();

    // MLP1: gelu(y @ Wd1)
    float yx[8];
    {
        float4v a = *(const float4v*)&s_yb[lm * 36 + quad * 8];
        float4v b = *(const float4v*)&s_yb[lm * 36 + quad * 8 + 4];
        yx[0]=a[0]; yx[1]=a[1]; yx[2]=a[2]; yx[3]=a[3];
        yx[4]=b[0]; yx[5]=b[1]; yx[6]=b[2]; yx[7]=b[3];
    }
    short8 yah, yal; split8(yx, yah, yal);
    float4v g0 = __builtin_amdgcn_mfma_f32_16x16x32_bf16(yal, wd1a, z, 0, 0, 0);
    g0 = __builtin_amdgcn_mfma_f32_16x16x32_bf16(yah, wd1a, g0, 0, 0, 0);
    float4v g1 = __builtin_amdgcn_mfma_f32_16x16x32_bf16(yal, wd1b, z, 0, 0, 0);
    g1 = __builtin_amdgcn_mfma_f32_16x16x32_bf16(yah, wd1b, g1, 0, 0, 0);
    float h0r[4], h1r[4];
    #pragma unroll
    for (int i = 0; i < 4; ++i) { h0r[i] = gelu_exact(g0[i]); h1r[i] = gelu_exact(g1[i]); }
    #pragma unroll
    for (int i = 0; i < 4; ++i) {       // reuse s_ctxb for h
        s_ctxb[(quad * 4 + i) * 36 + lm] = h0r[i];
        s_ctxb[(quad * 4 + i) * 36 + 16 + lm] = h1r[i];
    }
    WAVE_SYNC();

    // MLP2 + residual + store
    float hx[8];
    {
        float4v a = *(const float4v*)&s_ctxb[lm * 36 + quad * 8];
        float4v b = *(const float4v*)&s_ctxb[lm * 36 + quad * 8 + 4];
        hx[0]=a[0]; hx[1]=a[1]; hx[2]=a[2]; hx[3]=a[3];
        hx[4]=b[0]; hx[5]=b[1]; hx[6]=b[2]; hx[7]=b[3];
    }
    short8 hah, hal; split8(hx, hah, hal);
    float4v m0 = __builtin_amdgcn_mfma_f32_16x16x32_bf16(hal, wd2a, z, 0, 0, 0);
    m0 = __builtin_amdgcn_mfma_f32_16x16x32_bf16(hah, wd2a, m0, 0, 0, 0);
    float4v m1 = __builtin_amdgcn_mfma_f32_16x16x32_bf16(hal, wd2b, z, 0, 0, 0);
    m1 = __builtin_amdgcn_mfma_f32_16x16x32_bf16(hah, wd2b, m1, 0, 0, 0);

    #pragma unroll
    for (int i = 0; i < 4; ++i) {
        float f0 = y0r[i] + gelu_exact(m0[i]);
        float f1 = y1r[i] + gelu_exact(m1[i]);
        size_t ob = (size_t)(B0 + quad * 4 + i) * 32;
        out[ob + lm] = f0;
        out[ob + 16 + lm] = f1;
    }
}

extern "C" void kernel_launch(void* const* d_in, const int* in_sizes, int n_in,
                              void* d_out, int out_size, void* d_ws, size_t ws_size,
                              hipStream_t stream) {
    const float* query = (const float*)d_in[0];
    const float* kv    = (const float*)d_in[1];
    const float* Wq    = (const float*)d_in[2];
    const float* Wk    = (const float*)d_in[3];
    const float* Wv    = (const float*)d_in[4];
    const float* Wo    = (const float*)d_in[5];
    const float* ln_w  = (const float*)d_in[6];
    const float* ln_b  = (const float*)d_in[7];
    const float* Wd1   = (const float*)d_in[8];
    const float* Wd2   = (const float*)d_in[9];
    float* out = (float*)d_out;

    int B = in_sizes[0] / 13;        // 131072
    int grid = B / 16;               // 8192 blocks, 4 waves x 4 elements
    cross_dmha_fused<<<grid, 256, 0, stream>>>(
        query, kv, Wq, Wk, Wv, Wo, ln_w, ln_b, Wd1, Wd2, out);
}